// Round 6
// baseline (151.466 us; speedup 1.0000x reference)
//
#include <hip/hip_runtime.h>
#include <math.h>

#define N_NEU 256
#define D_DIM 32
#define KFD   16
#define KN    50
#define B_SZ  512
#define UINF  128
#define GAMMA 0.1f
#define DT    0.05f
#define NSTEP 20

#define TBL_K   4096
#define TBL_LO  (-64.0f)
#define TBL_IDL 32.0f          // 1/Delta ; Delta = 1/32, range [-64, +64)

typedef __attribute__((ext_vector_type(8))) short bf16x8;
typedef __attribute__((ext_vector_type(4))) float f32x4;

__device__ __forceinline__ unsigned short f2bf(float f) {
    unsigned u = __float_as_uint(f);
    u += 0x7FFFu + ((u >> 16) & 1u);     // round-to-nearest-even
    return (unsigned short)(u >> 16);
}
__device__ __forceinline__ float bf_lo(unsigned q) { return __uint_as_float(q << 16); }
__device__ __forceinline__ float bf_hi(unsigned q) { return __uint_as_float(q & 0xFFFF0000u); }

// ---------------------------------------------------------------------------
// Kernel 1: normalized-feature similarity + top-KN per row (unchanged).
// ---------------------------------------------------------------------------
__global__ __launch_bounds__(256) void topk_kernel(const float* __restrict__ features,
                                                   int* __restrict__ idxT,
                                                   float* __restrict__ vals2T) {
    __shared__ float fsh[N_NEU][KFD + 1];
    __shared__ float sim_sh[N_NEU];
    const int n = blockIdx.x;
    const int j = threadIdx.x;

    float v[KFD];
    float s = 0.f;
#pragma unroll
    for (int d = 0; d < KFD; ++d) { v[d] = features[j * KFD + d]; s = fmaf(v[d], v[d], s); }
    const float nrm = sqrtf(s);
#pragma unroll
    for (int d = 0; d < KFD; ++d) fsh[j][d] = v[d] / nrm;
    __syncthreads();

    float dot = 0.f;
#pragma unroll
    for (int d = 0; d < KFD; ++d) dot = fmaf(fsh[n][d], fsh[j][d], dot);
    sim_sh[j] = dot;
    __syncthreads();

    if (j < 64) {
        float l0 = sim_sh[j];
        float l1 = sim_sh[j + 64];
        float l2 = sim_sh[j + 128];
        float l3 = sim_sh[j + 192];
        for (int k = 0; k < KN; ++k) {
            float bv = l0; int bi = j;
            if (l1 > bv) { bv = l1; bi = j + 64; }
            if (l2 > bv) { bv = l2; bi = j + 128; }
            if (l3 > bv) { bv = l3; bi = j + 192; }
            for (int off = 32; off > 0; off >>= 1) {
                float ov = __shfl_xor(bv, off, 64);
                int   oi = __shfl_xor(bi, off, 64);
                if (ov > bv || (ov == bv && oi < bi)) { bv = ov; bi = oi; }
            }
            if (j == 0) {
                vals2T[(k >> 1) * (2 * N_NEU) + n * 2 + (k & 1)] = bv;
                idxT[k * N_NEU + n] = bi;
            }
            if ((bi & 63) == j) {
                const int q = bi >> 6;
                if      (q == 0) l0 = -INFINITY;
                else if (q == 1) l1 = -INFINITY;
                else if (q == 2) l2 = -INFINITY;
                else             l3 = -INFINITY;
            }
        }
    }
}

// ---------------------------------------------------------------------------
// Kernel 2: piecewise-linear table of G_d(s) (unchanged).
// ---------------------------------------------------------------------------
__global__ __launch_bounds__(256) void mlp_table_kernel(const float* __restrict__ sig_w1,
                                                        const float* __restrict__ sig_b1,
                                                        const float* __restrict__ sig_w2,
                                                        unsigned int* __restrict__ tbl) {
    const int gid = blockIdx.x * 256 + threadIdx.x;   // gid = k*32 + d
    const int k = gid >> 5, d = gid & 31;
    const float s0 = TBL_LO + (float)k / TBL_IDL;
    const float s1 = s0 + 1.0f / TBL_IDL;
    float g0 = 0.f, g1 = 0.f;
#pragma unroll
    for (int j = 0; j < 16; ++j) {
        const float w1 = sig_w1[j], b1 = sig_b1[j], w2 = sig_w2[d * 16 + j];
        const float h0 = fmaf(s0, w1, b1);
        const float h1 = fmaf(s1, w1, b1);
        const float e0 = 0.5f * h0 * (1.0f + erff(h0 * 0.70710678118654752f));
        const float e1 = 0.5f * h1 * (1.0f + erff(h1 * 0.70710678118654752f));
        g0 = fmaf(e0, w2, g0);
        g1 = fmaf(e1, w2, g1);
    }
    g0 *= DT; g1 *= DT;
    tbl[gid] = (unsigned int)f2bf(g0) | ((unsigned int)f2bf(g1 - g0) << 16);
}

// ---------------------------------------------------------------------------
// Kernel 3: uproj via bf16 MFMA (unchanged from round 5).
// ---------------------------------------------------------------------------
__global__ __launch_bounds__(256) void uproj_mfma_kernel(const float* __restrict__ u,
                                                         const float* __restrict__ w_in,
                                                         const float* __restrict__ b_in,
                                                         const float* __restrict__ bias,
                                                         const float* __restrict__ sig_b2,
                                                         float* __restrict__ cdt) {
    const int  wave = threadIdx.x >> 6;
    const int  lane = threadIdx.x & 63;
    const long m0   = (long)blockIdx.x * 64 + (long)wave * 16;
    const int  row  = lane & 15;
    const int  kg   = lane >> 4;

    bf16x8 bfrag[2][4];
#pragma unroll
    for (int dt_ = 0; dt_ < 2; ++dt_) {
#pragma unroll
        for (int kk = 0; kk < 4; ++kk) {
            const float* wp = w_in + (dt_ * 16 + row) * UINF + kk * 32 + kg * 8;
            bf16x8 f;
#pragma unroll
            for (int e = 0; e < 8; ++e) f[e] = (short)f2bf(wp[e]);
            bfrag[dt_][kk] = f;
        }
    }

    f32x4 acc0 = {0.f, 0.f, 0.f, 0.f};
    f32x4 acc1 = {0.f, 0.f, 0.f, 0.f};
#pragma unroll
    for (int kk = 0; kk < 4; ++kk) {
        const float* up = u + (m0 + row) * UINF + kk * 32 + kg * 8;
        const float4 a0 = *reinterpret_cast<const float4*>(up);
        const float4 a1 = *reinterpret_cast<const float4*>(up + 4);
        bf16x8 af;
        af[0] = (short)f2bf(a0.x); af[1] = (short)f2bf(a0.y);
        af[2] = (short)f2bf(a0.z); af[3] = (short)f2bf(a0.w);
        af[4] = (short)f2bf(a1.x); af[5] = (short)f2bf(a1.y);
        af[6] = (short)f2bf(a1.z); af[7] = (short)f2bf(a1.w);
        acc0 = __builtin_amdgcn_mfma_f32_16x16x32_bf16(af, bfrag[0][kk], acc0, 0, 0, 0);
        acc1 = __builtin_amdgcn_mfma_f32_16x16x32_bf16(af, bfrag[1][kk], acc1, 0, 0, 0);
    }

#pragma unroll
    for (int r = 0; r < 4; ++r) {
        const long m  = m0 + kg * 4 + r;
        const int  nn = (int)(m & (N_NEU - 1));
        const int  d0 = row;
        const int  d1 = 16 + row;
        cdt[m * D_DIM + d0] = DT * (acc0[r] + b_in[d0] + bias[nn * D_DIM + d0] + sig_b2[d0]);
        cdt[m * D_DIM + d1] = DT * (acc1[r] + b_in[d1] + bias[nn * D_DIM + d1] + sig_b2[d1]);
    }
}

// ---------------------------------------------------------------------------
// Kernel 4: 20-step recurrence, TWO batches per thread.
// Grid 256 x 256: thread owns neuron n for batches (blk, blk+256).
// The gather indices are batch-independent -> one ds_read_b64 of packed
// float2 a2_sh[ii] serves both batches; vals reads shared too. Per-batch LDS
// instructions: 75 -> 37.5 (the round-5 LDS-pipe bottleneck halves).
// State: x0[32]+x1[32] in regs; cdt + table streamed from L2 (keeps VGPR
// ~110 < 128 no-spill line). One barrier/step via double-buffered a2_sh.
// ---------------------------------------------------------------------------
__global__ __launch_bounds__(256) void steps_kernel(const float* __restrict__ cdt,
                                                    const int* __restrict__ idxT,
                                                    const float* __restrict__ vals2T,
                                                    const unsigned int* __restrict__ tbl,
                                                    float* __restrict__ out) {
    __shared__ float2 a2_sh[2][N_NEU];              // [buf][n] = (a_b0, a_b1)
    __shared__ float2 vals2_sh[(KN / 2) * N_NEU];   // 51200 B

    const int n  = threadIdx.x;
    const int b0 = blockIdx.x;
    const int b1 = blockIdx.x + 256;

    const float2* v2g = reinterpret_cast<const float2*>(vals2T);
    for (int i = n; i < (KN / 2) * N_NEU; i += 256) vals2_sh[i] = v2g[i];

    unsigned int idxp[13];
#pragma unroll
    for (int w = 0; w < 13; ++w) idxp[w] = 0u;
#pragma unroll
    for (int k = 0; k < KN; ++k) {
        const unsigned int ii = (unsigned int)idxT[k * N_NEU + n];
        idxp[k >> 2] |= ii << ((k & 3) * 8);
    }

    float x0[D_DIM], x1[D_DIM];
#pragma unroll
    for (int d = 0; d < D_DIM; ++d) { x0[d] = 0.f; x1[d] = 0.f; }

    const float4* cp0 = reinterpret_cast<const float4*>(cdt + ((size_t)b0 * N_NEU + n) * D_DIM);
    const float4* cp1 = reinterpret_cast<const float4*>(cdt + ((size_t)b1 * N_NEU + n) * D_DIM);
    const float K1 = 1.0f - DT * GAMMA;   // 0.995

    for (int s = 0; s < NSTEP; ++s) {
        float n0 = 1e-12f, n1 = 1e-12f;
#pragma unroll
        for (int d = 0; d < D_DIM; ++d) {
            n0 = fmaf(x0[d], x0[d], n0);
            n1 = fmaf(x1[d], x1[d], n1);
        }
        const float z0 = sqrtf(n0), z1 = sqrtf(n1);
        const float a0 = 1.0f - 2.0f / (__expf(2.0f * z0) + 1.0f);
        const float a1 = 1.0f - 2.0f / (__expf(2.0f * z1) + 1.0f);

        const int buf = s & 1;
        a2_sh[buf][n] = make_float2(a0, a1);
        __syncthreads();            // a visible (also covers initial staging)

        float sA0 = 0.f, sA1 = 0.f, sB0 = 0.f, sB1 = 0.f;
#pragma unroll
        for (int k2 = 0; k2 < KN / 2; ++k2) {
            const float2 vv = vals2_sh[k2 * N_NEU + n];
            const int k0 = 2 * k2, k1 = 2 * k2 + 1;
            const int i0 = (int)((idxp[k0 >> 2] >> ((k0 & 3) * 8)) & 255u);
            const int i1 = (int)((idxp[k1 >> 2] >> ((k1 & 3) * 8)) & 255u);
            const float2 g0 = a2_sh[buf][i0];
            const float2 g1 = a2_sh[buf][i1];
            sA0 = fmaf(g0.x, vv.x, sA0);
            sB0 = fmaf(g0.y, vv.x, sB0);
            sA1 = fmaf(g1.x, vv.y, sA1);
            sB1 = fmaf(g1.y, vv.y, sB1);
        }
        const float synA = sA0 + sA1;   // batch b0
        const float synB = sB0 + sB1;   // batch b1

        // x <- K1*x + cdt (cdt pre-scaled by DT; L2-hot, 64 KB/block slice)
#pragma unroll
        for (int i = 0; i < 8; ++i) {
            const float4 c0 = cp0[i];
            const float4 c1 = cp1[i];
            x0[4 * i + 0] = fmaf(K1, x0[4 * i + 0], c0.x);
            x0[4 * i + 1] = fmaf(K1, x0[4 * i + 1], c0.y);
            x0[4 * i + 2] = fmaf(K1, x0[4 * i + 2], c0.z);
            x0[4 * i + 3] = fmaf(K1, x0[4 * i + 3], c0.w);
            x1[4 * i + 0] = fmaf(K1, x1[4 * i + 0], c1.x);
            x1[4 * i + 1] = fmaf(K1, x1[4 * i + 1], c1.y);
            x1[4 * i + 2] = fmaf(K1, x1[4 * i + 2], c1.z);
            x1[4 * i + 3] = fmaf(K1, x1[4 * i + 3], c1.w);
        }

        // sigma MLP via table lerp, once per batch
        const float uA = fmaf(synA, TBL_IDL, -TBL_LO * TBL_IDL);
        const float uB = fmaf(synB, TBL_IDL, -TBL_LO * TBL_IDL);
        int iA = (int)floorf(uA);
        int iB = (int)floorf(uB);
        iA = (iA < 0) ? 0 : (iA > TBL_K - 2 ? TBL_K - 2 : iA);
        iB = (iB < 0) ? 0 : (iB > TBL_K - 2 ? TBL_K - 2 : iB);
        const float tA = uA - (float)iA;
        const float tB = uB - (float)iB;
        const uint4* rpA = reinterpret_cast<const uint4*>(tbl + (size_t)iA * 32);
        const uint4* rpB = reinterpret_cast<const uint4*>(tbl + (size_t)iB * 32);
#pragma unroll 2
        for (int c = 0; c < 8; ++c) {
            const uint4 qA = rpA[c];
            const uint4 qB = rpB[c];
            x0[4 * c + 0] = fmaf(tA, bf_hi(qA.x), x0[4 * c + 0] + bf_lo(qA.x));
            x0[4 * c + 1] = fmaf(tA, bf_hi(qA.y), x0[4 * c + 1] + bf_lo(qA.y));
            x0[4 * c + 2] = fmaf(tA, bf_hi(qA.z), x0[4 * c + 2] + bf_lo(qA.z));
            x0[4 * c + 3] = fmaf(tA, bf_hi(qA.w), x0[4 * c + 3] + bf_lo(qA.w));
            x1[4 * c + 0] = fmaf(tB, bf_hi(qB.x), x1[4 * c + 0] + bf_lo(qB.x));
            x1[4 * c + 1] = fmaf(tB, bf_hi(qB.y), x1[4 * c + 1] + bf_lo(qB.y));
            x1[4 * c + 2] = fmaf(tB, bf_hi(qB.z), x1[4 * c + 2] + bf_lo(qB.z));
            x1[4 * c + 3] = fmaf(tB, bf_hi(qB.w), x1[4 * c + 3] + bf_lo(qB.w));
        }
    }

    float4* op0 = reinterpret_cast<float4*>(out + ((size_t)b0 * N_NEU + n) * D_DIM);
    float4* op1 = reinterpret_cast<float4*>(out + ((size_t)b1 * N_NEU + n) * D_DIM);
#pragma unroll
    for (int i = 0; i < 8; ++i) {
        op0[i] = make_float4(x0[4 * i + 0], x0[4 * i + 1], x0[4 * i + 2], x0[4 * i + 3]);
        op1[i] = make_float4(x1[4 * i + 0], x1[4 * i + 1], x1[4 * i + 2], x1[4 * i + 3]);
    }
}

extern "C" void kernel_launch(void* const* d_in, const int* in_sizes, int n_in,
                              void* d_out, int out_size, void* d_ws, size_t ws_size,
                              hipStream_t stream) {
    const float* u        = (const float*)d_in[0];
    const float* features = (const float*)d_in[1];
    const float* bias     = (const float*)d_in[2];
    const float* w_in     = (const float*)d_in[3];
    const float* b_in     = (const float*)d_in[4];
    const float* sig_w1   = (const float*)d_in[5];
    const float* sig_b1   = (const float*)d_in[6];
    const float* sig_w2   = (const float*)d_in[7];
    const float* sig_b2   = (const float*)d_in[8];
    float* out = (float*)d_out;

    char*         ws     = (char*)d_ws;
    int*          idxT   = (int*)ws;                      // 51200 B
    float*        vals2T = (float*)(ws + 51200);          // 51200 B
    unsigned int* tbl    = (unsigned int*)(ws + 102400);  // 512 KiB
    float*        cdt    = (float*)(ws + 102400 + 524288);// 16 MiB

    hipLaunchKernelGGL(topk_kernel, dim3(N_NEU), dim3(256), 0, stream,
                       features, idxT, vals2T);
    hipLaunchKernelGGL(mlp_table_kernel, dim3(TBL_K * 32 / 256), dim3(256), 0, stream,
                       sig_w1, sig_b1, sig_w2, tbl);
    hipLaunchKernelGGL(uproj_mfma_kernel, dim3(B_SZ * N_NEU / 64), dim3(256), 0, stream,
                       u, w_in, b_in, bias, sig_b2, cdt);
    hipLaunchKernelGGL(steps_kernel, dim3(B_SZ / 2), dim3(256), 0, stream,
                       cdt, idxT, vals2T, tbl, out);
}

// Round 7
// 118.315 us; speedup vs baseline: 1.2802x; 1.2802x over previous
//
#include <hip/hip_runtime.h>
#include <math.h>

#define N_NEU 256
#define D_DIM 32
#define KFD   16
#define KN    50
#define B_SZ  512
#define UINF  128
#define GAMMA 0.1f
#define DT    0.05f
#define NSTEP 20

#define TBL_K   4096
#define TBL_LO  (-64.0f)
#define TBL_IDL 32.0f          // 1/Delta ; Delta = 1/32, range [-64, +64)

// pre_kernel grid layout
#define UPROJ_BLKS (B_SZ * N_NEU / 64)   // 2048
#define TOPK_BLKS  N_NEU                 // 256
#define TBL_BLKS   (TBL_K * 32 / 256)    // 512

typedef __attribute__((ext_vector_type(8))) short bf16x8;
typedef __attribute__((ext_vector_type(4))) float f32x4;

__device__ __forceinline__ unsigned short f2bf(float f) {
    unsigned u = __float_as_uint(f);
    u += 0x7FFFu + ((u >> 16) & 1u);     // round-to-nearest-even
    return (unsigned short)(u >> 16);
}
__device__ __forceinline__ float bf_lo(unsigned q) { return __uint_as_float(q << 16); }
__device__ __forceinline__ float bf_hi(unsigned q) { return __uint_as_float(q & 0xFFFF0000u); }

// ---------------------------------------------------------------------------
// Fused pre-kernel: [0,2048) uproj-MFMA | [2048,2304) topk | [2304,2816) table.
// Fusion hides the two tiny kernels under uproj's HBM time and removes
// 2 launch gaps. All branches use 256 threads.
// vals are written ZERO-PADDED to 52 and in split-half pair layout:
//   float2 [jj][n*2+h], jj<13: half h of neuron n, pair jj = (k-h*26)/2.
// ---------------------------------------------------------------------------
__global__ __launch_bounds__(256) void pre_kernel(const float* __restrict__ u,
                                                  const float* __restrict__ w_in,
                                                  const float* __restrict__ b_in,
                                                  const float* __restrict__ bias,
                                                  const float* __restrict__ sig_b2,
                                                  const float* __restrict__ features,
                                                  const float* __restrict__ sig_w1,
                                                  const float* __restrict__ sig_b1,
                                                  const float* __restrict__ sig_w2,
                                                  int* __restrict__ idxT,
                                                  float* __restrict__ vals2T,
                                                  unsigned int* __restrict__ tbl,
                                                  float* __restrict__ cdt) {
    __shared__ float fsh[N_NEU][KFD + 1];
    __shared__ float sim_sh[N_NEU];

    const int bid = blockIdx.x;

    if (bid < UPROJ_BLKS) {
        // ---- uproj via bf16 MFMA ----
        const int  wave = threadIdx.x >> 6;
        const int  lane = threadIdx.x & 63;
        const long m0   = (long)bid * 64 + (long)wave * 16;
        const int  row  = lane & 15;
        const int  kg   = lane >> 4;

        bf16x8 bfrag[2][4];
#pragma unroll
        for (int dt_ = 0; dt_ < 2; ++dt_) {
#pragma unroll
            for (int kk = 0; kk < 4; ++kk) {
                const float* wp = w_in + (dt_ * 16 + row) * UINF + kk * 32 + kg * 8;
                bf16x8 f;
#pragma unroll
                for (int e = 0; e < 8; ++e) f[e] = (short)f2bf(wp[e]);
                bfrag[dt_][kk] = f;
            }
        }

        f32x4 acc0 = {0.f, 0.f, 0.f, 0.f};
        f32x4 acc1 = {0.f, 0.f, 0.f, 0.f};
#pragma unroll
        for (int kk = 0; kk < 4; ++kk) {
            const float* up = u + (m0 + row) * UINF + kk * 32 + kg * 8;
            const float4 a0 = *reinterpret_cast<const float4*>(up);
            const float4 a1 = *reinterpret_cast<const float4*>(up + 4);
            bf16x8 af;
            af[0] = (short)f2bf(a0.x); af[1] = (short)f2bf(a0.y);
            af[2] = (short)f2bf(a0.z); af[3] = (short)f2bf(a0.w);
            af[4] = (short)f2bf(a1.x); af[5] = (short)f2bf(a1.y);
            af[6] = (short)f2bf(a1.z); af[7] = (short)f2bf(a1.w);
            acc0 = __builtin_amdgcn_mfma_f32_16x16x32_bf16(af, bfrag[0][kk], acc0, 0, 0, 0);
            acc1 = __builtin_amdgcn_mfma_f32_16x16x32_bf16(af, bfrag[1][kk], acc1, 0, 0, 0);
        }

#pragma unroll
        for (int r = 0; r < 4; ++r) {
            const long m  = m0 + kg * 4 + r;
            const int  nn = (int)(m & (N_NEU - 1));
            const int  d0 = row;
            const int  d1 = 16 + row;
            cdt[m * D_DIM + d0] = DT * (acc0[r] + b_in[d0] + bias[nn * D_DIM + d0] + sig_b2[d0]);
            cdt[m * D_DIM + d1] = DT * (acc1[r] + b_in[d1] + bias[nn * D_DIM + d1] + sig_b2[d1]);
        }
    } else if (bid < UPROJ_BLKS + TOPK_BLKS) {
        // ---- topk ----
        const int n = bid - UPROJ_BLKS;
        const int j = threadIdx.x;

        float v[KFD];
        float s = 0.f;
#pragma unroll
        for (int d = 0; d < KFD; ++d) { v[d] = features[j * KFD + d]; s = fmaf(v[d], v[d], s); }
        const float nrm = sqrtf(s);
#pragma unroll
        for (int d = 0; d < KFD; ++d) fsh[j][d] = v[d] / nrm;
        __syncthreads();

        float dot = 0.f;
#pragma unroll
        for (int d = 0; d < KFD; ++d) dot = fmaf(fsh[n][d], fsh[j][d], dot);
        sim_sh[j] = dot;
        __syncthreads();

        if (j < 64) {
            float l0 = sim_sh[j];
            float l1 = sim_sh[j + 64];
            float l2 = sim_sh[j + 128];
            float l3 = sim_sh[j + 192];
            for (int k = 0; k < KN; ++k) {
                float bv = l0; int bi = j;
                if (l1 > bv) { bv = l1; bi = j + 64; }
                if (l2 > bv) { bv = l2; bi = j + 128; }
                if (l3 > bv) { bv = l3; bi = j + 192; }
                for (int off = 32; off > 0; off >>= 1) {
                    float ov = __shfl_xor(bv, off, 64);
                    int   oi = __shfl_xor(bi, off, 64);
                    if (ov > bv || (ov == bv && oi < bi)) { bv = ov; bi = oi; }
                }
                if (j == 0) {
                    int fi;
                    if (k < 26) fi = (k >> 1) * 1024 + n * 4 + (k & 1);
                    else { const int kk = k - 26; fi = (kk >> 1) * 1024 + n * 4 + 2 + (kk & 1); }
                    vals2T[fi] = bv;
                    idxT[k * N_NEU + n] = bi;
                }
                if ((bi & 63) == j) {
                    const int q = bi >> 6;
                    if      (q == 0) l0 = -INFINITY;
                    else if (q == 1) l1 = -INFINITY;
                    else if (q == 2) l2 = -INFINITY;
                    else             l3 = -INFINITY;
                }
            }
            if (j == 0) {   // zero-pad k = 50,51 (half 1, pair 12)
                vals2T[12 * 1024 + n * 4 + 2] = 0.f;
                vals2T[12 * 1024 + n * 4 + 3] = 0.f;
            }
        }
    } else {
        // ---- mlp table ----
        const int gid = (bid - UPROJ_BLKS - TOPK_BLKS) * 256 + threadIdx.x;  // k*32+d
        const int k = gid >> 5, d = gid & 31;
        const float s0 = TBL_LO + (float)k / TBL_IDL;
        const float s1 = s0 + 1.0f / TBL_IDL;
        float g0 = 0.f, g1 = 0.f;
#pragma unroll
        for (int j = 0; j < 16; ++j) {
            const float w1 = sig_w1[j], b1 = sig_b1[j], w2 = sig_w2[d * 16 + j];
            const float h0 = fmaf(s0, w1, b1);
            const float h1 = fmaf(s1, w1, b1);
            const float e0 = 0.5f * h0 * (1.0f + erff(h0 * 0.70710678118654752f));
            const float e1 = 0.5f * h1 * (1.0f + erff(h1 * 0.70710678118654752f));
            g0 = fmaf(e0, w2, g0);
            g1 = fmaf(e1, w2, g1);
        }
        g0 *= DT; g1 *= DT;
        tbl[gid] = (unsigned int)f2bf(g0) | ((unsigned int)f2bf(g1 - g0) << 16);
    }
}

// ---------------------------------------------------------------------------
// Steps kernel v7: split-(batch,neuron) across a LANE PAIR.
// Grid 512 x 512 threads: block = 1 batch, thread t -> neuron n = t>>1,
// half h = t&1 (owns 16 of 32 x-dims, 26 of 52 zero-padded gathers).
// Partner exchanges (partial norm, partial syn) via __shfl_xor(.,1) — same
// wave, no LDS, no extra barrier. One barrier/step (double-buffered a_sh).
// Occupancy: 2 blocks/CU x 8 waves = 16 waves/CU (2x round 5 — the round-6
// experiment showed steps is latency-bound, so TLP is the lever).
// Per-thread-step LDS: 26 gathers + 13 float2 vals = 39 instr (vs 75).
// ---------------------------------------------------------------------------
__global__ __launch_bounds__(512) void steps_kernel(const float* __restrict__ cdt,
                                                    const int* __restrict__ idxT,
                                                    const float* __restrict__ vals2T,
                                                    const unsigned int* __restrict__ tbl,
                                                    float* __restrict__ out) {
    __shared__ float  a_sh[2][N_NEU];
    __shared__ float2 vals_sh[13 * 512];   // [jj][n*2+h], 53248 B

    const int t = threadIdx.x;
    const int n = t >> 1;
    const int h = t & 1;
    const int b = blockIdx.x;

    const float2* v2g = reinterpret_cast<const float2*>(vals2T);
    for (int i = t; i < 13 * 512; i += 512) vals_sh[i] = v2g[i];

    // pack this thread's 26 neighbor indices (k = h*26 + j), idx<256 -> 8 bit
    unsigned int idxp[7];
#pragma unroll
    for (int w = 0; w < 7; ++w) idxp[w] = 0u;
#pragma unroll
    for (int j = 0; j < 26; ++j) {
        const int k = h * 26 + j;
        const unsigned int ii = (k < KN) ? (unsigned int)idxT[k * N_NEU + n] : 0u;
        idxp[j >> 2] |= ii << ((j & 3) * 8);
    }

    float x[16], ccdt[16];
    const float4* cp4 = reinterpret_cast<const float4*>(cdt + ((size_t)b * N_NEU + n) * D_DIM + h * 16);
#pragma unroll
    for (int i = 0; i < 4; ++i) {
        const float4 cv = cp4[i];
        ccdt[4 * i + 0] = cv.x; ccdt[4 * i + 1] = cv.y;
        ccdt[4 * i + 2] = cv.z; ccdt[4 * i + 3] = cv.w;
    }
#pragma unroll
    for (int d = 0; d < 16; ++d) x[d] = 0.f;
    __syncthreads();   // vals_sh staged

    const float K1 = 1.0f - DT * GAMMA;   // 0.995

    for (int s = 0; s < NSTEP; ++s) {
        // ---- firing rate: partial norm + lane-pair exchange ----
        float nh = 0.f;
#pragma unroll
        for (int d = 0; d < 16; ++d) nh = fmaf(x[d], x[d], nh);
        const float nfull = nh + __shfl_xor(nh, 1, 64) + 1e-12f;
        const float z = sqrtf(nfull);
        const float a = 1.0f - 2.0f / (__expf(2.0f * z) + 1.0f);   // tanh(z), z>=0

        const int buf = s & 1;
        if (h == 0) a_sh[buf][n] = a;
        __syncthreads();            // a visible; WAR safe via double buffer

        // ---- 26 gathers (13 float2 vals), 4 accumulators ----
        float s0 = 0.f, s1 = 0.f, s2 = 0.f, s3 = 0.f;
#pragma unroll
        for (int jj = 0; jj < 13; ++jj) {
            const float2 vv = vals_sh[jj * 512 + t];
            const int j0 = 2 * jj, j1 = 2 * jj + 1;
            const int i0 = (int)((idxp[j0 >> 2] >> ((j0 & 3) * 8)) & 255u);
            const int i1 = (int)((idxp[j1 >> 2] >> ((j1 & 3) * 8)) & 255u);
            if (jj & 1) { s2 = fmaf(a_sh[buf][i0], vv.x, s2); s3 = fmaf(a_sh[buf][i1], vv.y, s3); }
            else        { s0 = fmaf(a_sh[buf][i0], vv.x, s0); s1 = fmaf(a_sh[buf][i1], vv.y, s1); }
        }
        const float synh = (s0 + s1) + (s2 + s3);
        const float syn  = synh + __shfl_xor(synh, 1, 64);

        // ---- x <- K1*x + cdt (this thread's 16 dims) ----
#pragma unroll
        for (int d = 0; d < 16; ++d) x[d] = fmaf(K1, x[d], ccdt[d]);

        // ---- sigma MLP via table lerp (this thread's 16 dims) ----
        const float uu = fmaf(syn, TBL_IDL, -TBL_LO * TBL_IDL);
        int i = (int)floorf(uu);
        i = (i < 0) ? 0 : (i > TBL_K - 2 ? TBL_K - 2 : i);
        const float tf = uu - (float)i;
        const uint4* rp = reinterpret_cast<const uint4*>(tbl + (size_t)i * 32 + h * 16);
#pragma unroll
        for (int c = 0; c < 4; ++c) {
            const uint4 q = rp[c];
            x[4 * c + 0] = fmaf(tf, bf_hi(q.x), x[4 * c + 0] + bf_lo(q.x));
            x[4 * c + 1] = fmaf(tf, bf_hi(q.y), x[4 * c + 1] + bf_lo(q.y));
            x[4 * c + 2] = fmaf(tf, bf_hi(q.z), x[4 * c + 2] + bf_lo(q.z));
            x[4 * c + 3] = fmaf(tf, bf_hi(q.w), x[4 * c + 3] + bf_lo(q.w));
        }
    }

    float4* op4 = reinterpret_cast<float4*>(out + ((size_t)b * N_NEU + n) * D_DIM + h * 16);
#pragma unroll
    for (int i = 0; i < 4; ++i)
        op4[i] = make_float4(x[4 * i + 0], x[4 * i + 1], x[4 * i + 2], x[4 * i + 3]);
}

extern "C" void kernel_launch(void* const* d_in, const int* in_sizes, int n_in,
                              void* d_out, int out_size, void* d_ws, size_t ws_size,
                              hipStream_t stream) {
    const float* u        = (const float*)d_in[0];
    const float* features = (const float*)d_in[1];
    const float* bias     = (const float*)d_in[2];
    const float* w_in     = (const float*)d_in[3];
    const float* b_in     = (const float*)d_in[4];
    const float* sig_w1   = (const float*)d_in[5];
    const float* sig_b1   = (const float*)d_in[6];
    const float* sig_w2   = (const float*)d_in[7];
    const float* sig_b2   = (const float*)d_in[8];
    float* out = (float*)d_out;

    char*         ws     = (char*)d_ws;
    int*          idxT   = (int*)ws;                      // 51200 B
    float*        vals2T = (float*)(ws + 51200);          // 13*512*8 = 53248 B
    unsigned int* tbl    = (unsigned int*)(ws + 107520);  // 512 KiB
    float*        cdt    = (float*)(ws + 107520 + 524288);// 16 MiB

    hipLaunchKernelGGL(pre_kernel, dim3(UPROJ_BLKS + TOPK_BLKS + TBL_BLKS), dim3(256), 0, stream,
                       u, w_in, b_in, bias, sig_b2, features, sig_w1, sig_b1, sig_w2,
                       idxT, vals2T, tbl, cdt);
    hipLaunchKernelGGL(steps_kernel, dim3(B_SZ), dim3(512), 0, stream,
                       cdt, idxT, vals2T, tbl, out);
}

// Round 8
// 102.516 us; speedup vs baseline: 1.4775x; 1.1541x over previous
//
#include <hip/hip_runtime.h>
#include <math.h>

#define N_NEU 256
#define D_DIM 32
#define KFD   16
#define KN    50
#define B_SZ  512
#define UINF  128
#define GAMMA 0.1f
#define DT    0.05f
#define NSTEP 20

#define TBL_K   4096
#define TBL_LO  (-64.0f)
#define TBL_IDL 32.0f          // 1/Delta ; Delta = 1/32, range [-64, +64)

// pre_kernel grid layout: 256 rows of u per uproj block (4 m-tiles per wave)
#define UPROJ_BLKS (B_SZ * N_NEU / 256)  // 512
#define TOPK_BLKS  N_NEU                 // 256
#define TBL_BLKS   (TBL_K * 32 / 256)    // 512

typedef __attribute__((ext_vector_type(8))) short bf16x8;
typedef __attribute__((ext_vector_type(4))) float f32x4;

__device__ __forceinline__ unsigned short f2bf(float f) {
    unsigned u = __float_as_uint(f);
    u += 0x7FFFu + ((u >> 16) & 1u);     // round-to-nearest-even
    return (unsigned short)(u >> 16);
}
__device__ __forceinline__ float bf_lo(unsigned q) { return __uint_as_float(q << 16); }
__device__ __forceinline__ float bf_hi(unsigned q) { return __uint_as_float(q & 0xFFFF0000u); }

// ---------------------------------------------------------------------------
// Fused pre-kernel: [0,512) uproj-MFMA | [512,768) topk | [768,1280) table.
// uproj: wave = 64 rows (4 m-tiles), block = 256 rows. Round-7's 16-rows/wave
// version was latency-bound (11 block-generations/CU, ~212 cyc/load fully
// exposed). Here w_in fragments load once/wave, and the t4 x kk unroll gives
// 32 independent u-loads + 32 MFMA per wave -> MLP hides the latency.
// ---------------------------------------------------------------------------
__global__ __launch_bounds__(256) void pre_kernel(const float* __restrict__ u,
                                                  const float* __restrict__ w_in,
                                                  const float* __restrict__ b_in,
                                                  const float* __restrict__ bias,
                                                  const float* __restrict__ sig_b2,
                                                  const float* __restrict__ features,
                                                  const float* __restrict__ sig_w1,
                                                  const float* __restrict__ sig_b1,
                                                  const float* __restrict__ sig_w2,
                                                  int* __restrict__ idxT,
                                                  float* __restrict__ vals2T,
                                                  unsigned int* __restrict__ tbl,
                                                  float* __restrict__ cdt) {
    __shared__ float fsh[N_NEU][KFD + 1];
    __shared__ float sim_sh[N_NEU];

    const int bid = blockIdx.x;

    if (bid < UPROJ_BLKS) {
        // ---- uproj via bf16 MFMA, 4 m-tiles per wave ----
        const int  wave = threadIdx.x >> 6;
        const int  lane = threadIdx.x & 63;
        const long m0   = (long)bid * 256 + (long)wave * 64;
        const int  row  = lane & 15;
        const int  kg   = lane >> 4;

        bf16x8 bfrag[2][4];
#pragma unroll
        for (int dt_ = 0; dt_ < 2; ++dt_) {
#pragma unroll
            for (int kk = 0; kk < 4; ++kk) {
                const float* wp = w_in + (dt_ * 16 + row) * UINF + kk * 32 + kg * 8;
                bf16x8 f;
#pragma unroll
                for (int e = 0; e < 8; ++e) f[e] = (short)f2bf(wp[e]);
                bfrag[dt_][kk] = f;
            }
        }

        f32x4 acc[4][2];
#pragma unroll
        for (int t4 = 0; t4 < 4; ++t4) {
            acc[t4][0] = (f32x4){0.f, 0.f, 0.f, 0.f};
            acc[t4][1] = (f32x4){0.f, 0.f, 0.f, 0.f};
        }

#pragma unroll
        for (int t4 = 0; t4 < 4; ++t4) {
#pragma unroll
            for (int kk = 0; kk < 4; ++kk) {
                const float* up = u + (m0 + t4 * 16 + row) * UINF + kk * 32 + kg * 8;
                const float4 a0 = *reinterpret_cast<const float4*>(up);
                const float4 a1 = *reinterpret_cast<const float4*>(up + 4);
                bf16x8 af;
                af[0] = (short)f2bf(a0.x); af[1] = (short)f2bf(a0.y);
                af[2] = (short)f2bf(a0.z); af[3] = (short)f2bf(a0.w);
                af[4] = (short)f2bf(a1.x); af[5] = (short)f2bf(a1.y);
                af[6] = (short)f2bf(a1.z); af[7] = (short)f2bf(a1.w);
                acc[t4][0] = __builtin_amdgcn_mfma_f32_16x16x32_bf16(af, bfrag[0][kk], acc[t4][0], 0, 0, 0);
                acc[t4][1] = __builtin_amdgcn_mfma_f32_16x16x32_bf16(af, bfrag[1][kk], acc[t4][1], 0, 0, 0);
            }
        }

        const int   d0   = row;
        const int   d1   = 16 + row;
        const float add0 = b_in[d0] + sig_b2[d0];
        const float add1 = b_in[d1] + sig_b2[d1];
#pragma unroll
        for (int t4 = 0; t4 < 4; ++t4) {
#pragma unroll
            for (int r = 0; r < 4; ++r) {
                const long m  = m0 + t4 * 16 + kg * 4 + r;
                const int  nn = (int)(m & (N_NEU - 1));
                cdt[m * D_DIM + d0] = DT * (acc[t4][0][r] + add0 + bias[nn * D_DIM + d0]);
                cdt[m * D_DIM + d1] = DT * (acc[t4][1][r] + add1 + bias[nn * D_DIM + d1]);
            }
        }
    } else if (bid < UPROJ_BLKS + TOPK_BLKS) {
        // ---- topk ----
        const int n = bid - UPROJ_BLKS;
        const int j = threadIdx.x;

        float v[KFD];
        float s = 0.f;
#pragma unroll
        for (int d = 0; d < KFD; ++d) { v[d] = features[j * KFD + d]; s = fmaf(v[d], v[d], s); }
        const float nrm = sqrtf(s);
#pragma unroll
        for (int d = 0; d < KFD; ++d) fsh[j][d] = v[d] / nrm;
        __syncthreads();

        float dot = 0.f;
#pragma unroll
        for (int d = 0; d < KFD; ++d) dot = fmaf(fsh[n][d], fsh[j][d], dot);
        sim_sh[j] = dot;
        __syncthreads();

        if (j < 64) {
            float l0 = sim_sh[j];
            float l1 = sim_sh[j + 64];
            float l2 = sim_sh[j + 128];
            float l3 = sim_sh[j + 192];
            for (int k = 0; k < KN; ++k) {
                float bv = l0; int bi = j;
                if (l1 > bv) { bv = l1; bi = j + 64; }
                if (l2 > bv) { bv = l2; bi = j + 128; }
                if (l3 > bv) { bv = l3; bi = j + 192; }
                for (int off = 32; off > 0; off >>= 1) {
                    float ov = __shfl_xor(bv, off, 64);
                    int   oi = __shfl_xor(bi, off, 64);
                    if (ov > bv || (ov == bv && oi < bi)) { bv = ov; bi = oi; }
                }
                if (j == 0) {
                    int fi;
                    if (k < 26) fi = (k >> 1) * 1024 + n * 4 + (k & 1);
                    else { const int kk = k - 26; fi = (kk >> 1) * 1024 + n * 4 + 2 + (kk & 1); }
                    vals2T[fi] = bv;
                    idxT[k * N_NEU + n] = bi;
                }
                if ((bi & 63) == j) {
                    const int q = bi >> 6;
                    if      (q == 0) l0 = -INFINITY;
                    else if (q == 1) l1 = -INFINITY;
                    else if (q == 2) l2 = -INFINITY;
                    else             l3 = -INFINITY;
                }
            }
            if (j == 0) {   // zero-pad k = 50,51 (half 1, pair 12)
                vals2T[12 * 1024 + n * 4 + 2] = 0.f;
                vals2T[12 * 1024 + n * 4 + 3] = 0.f;
            }
        }
    } else {
        // ---- mlp table ----
        const int gid = (bid - UPROJ_BLKS - TOPK_BLKS) * 256 + threadIdx.x;  // k*32+d
        const int k = gid >> 5, d = gid & 31;
        const float s0 = TBL_LO + (float)k / TBL_IDL;
        const float s1 = s0 + 1.0f / TBL_IDL;
        float g0 = 0.f, g1 = 0.f;
#pragma unroll
        for (int j = 0; j < 16; ++j) {
            const float w1 = sig_w1[j], b1 = sig_b1[j], w2 = sig_w2[d * 16 + j];
            const float h0 = fmaf(s0, w1, b1);
            const float h1 = fmaf(s1, w1, b1);
            const float e0 = 0.5f * h0 * (1.0f + erff(h0 * 0.70710678118654752f));
            const float e1 = 0.5f * h1 * (1.0f + erff(h1 * 0.70710678118654752f));
            g0 = fmaf(e0, w2, g0);
            g1 = fmaf(e1, w2, g1);
        }
        g0 *= DT; g1 *= DT;
        tbl[gid] = (unsigned int)f2bf(g0) | ((unsigned int)f2bf(g1 - g0) << 16);
    }
}

// ---------------------------------------------------------------------------
// Steps kernel (unchanged from round 7): split-(batch,neuron) across a lane
// pair. Grid 512 x 512: block = 1 batch, thread t -> neuron n=t>>1, half h=t&1.
// Partner exchange via __shfl_xor(.,1); one barrier/step; 16 waves/CU.
// ---------------------------------------------------------------------------
__global__ __launch_bounds__(512) void steps_kernel(const float* __restrict__ cdt,
                                                    const int* __restrict__ idxT,
                                                    const float* __restrict__ vals2T,
                                                    const unsigned int* __restrict__ tbl,
                                                    float* __restrict__ out) {
    __shared__ float  a_sh[2][N_NEU];
    __shared__ float2 vals_sh[13 * 512];   // [jj][n*2+h], 53248 B

    const int t = threadIdx.x;
    const int n = t >> 1;
    const int h = t & 1;
    const int b = blockIdx.x;

    const float2* v2g = reinterpret_cast<const float2*>(vals2T);
    for (int i = t; i < 13 * 512; i += 512) vals_sh[i] = v2g[i];

    unsigned int idxp[7];
#pragma unroll
    for (int w = 0; w < 7; ++w) idxp[w] = 0u;
#pragma unroll
    for (int j = 0; j < 26; ++j) {
        const int k = h * 26 + j;
        const unsigned int ii = (k < KN) ? (unsigned int)idxT[k * N_NEU + n] : 0u;
        idxp[j >> 2] |= ii << ((j & 3) * 8);
    }

    float x[16], ccdt[16];
    const float4* cp4 = reinterpret_cast<const float4*>(cdt + ((size_t)b * N_NEU + n) * D_DIM + h * 16);
#pragma unroll
    for (int i = 0; i < 4; ++i) {
        const float4 cv = cp4[i];
        ccdt[4 * i + 0] = cv.x; ccdt[4 * i + 1] = cv.y;
        ccdt[4 * i + 2] = cv.z; ccdt[4 * i + 3] = cv.w;
    }
#pragma unroll
    for (int d = 0; d < 16; ++d) x[d] = 0.f;
    __syncthreads();   // vals_sh staged

    const float K1 = 1.0f - DT * GAMMA;   // 0.995

    for (int s = 0; s < NSTEP; ++s) {
        float nh = 0.f;
#pragma unroll
        for (int d = 0; d < 16; ++d) nh = fmaf(x[d], x[d], nh);
        const float nfull = nh + __shfl_xor(nh, 1, 64) + 1e-12f;
        const float z = sqrtf(nfull);
        const float a = 1.0f - 2.0f / (__expf(2.0f * z) + 1.0f);   // tanh(z), z>=0

        const int buf = s & 1;
        if (h == 0) a_sh[buf][n] = a;
        __syncthreads();            // a visible; WAR safe via double buffer

        float s0 = 0.f, s1 = 0.f, s2 = 0.f, s3 = 0.f;
#pragma unroll
        for (int jj = 0; jj < 13; ++jj) {
            const float2 vv = vals_sh[jj * 512 + t];
            const int j0 = 2 * jj, j1 = 2 * jj + 1;
            const int i0 = (int)((idxp[j0 >> 2] >> ((j0 & 3) * 8)) & 255u);
            const int i1 = (int)((idxp[j1 >> 2] >> ((j1 & 3) * 8)) & 255u);
            if (jj & 1) { s2 = fmaf(a_sh[buf][i0], vv.x, s2); s3 = fmaf(a_sh[buf][i1], vv.y, s3); }
            else        { s0 = fmaf(a_sh[buf][i0], vv.x, s0); s1 = fmaf(a_sh[buf][i1], vv.y, s1); }
        }
        const float synh = (s0 + s1) + (s2 + s3);
        const float syn  = synh + __shfl_xor(synh, 1, 64);

#pragma unroll
        for (int d = 0; d < 16; ++d) x[d] = fmaf(K1, x[d], ccdt[d]);

        const float uu = fmaf(syn, TBL_IDL, -TBL_LO * TBL_IDL);
        int i = (int)floorf(uu);
        i = (i < 0) ? 0 : (i > TBL_K - 2 ? TBL_K - 2 : i);
        const float tf = uu - (float)i;
        const uint4* rp = reinterpret_cast<const uint4*>(tbl + (size_t)i * 32 + h * 16);
#pragma unroll
        for (int c = 0; c < 4; ++c) {
            const uint4 q = rp[c];
            x[4 * c + 0] = fmaf(tf, bf_hi(q.x), x[4 * c + 0] + bf_lo(q.x));
            x[4 * c + 1] = fmaf(tf, bf_hi(q.y), x[4 * c + 1] + bf_lo(q.y));
            x[4 * c + 2] = fmaf(tf, bf_hi(q.z), x[4 * c + 2] + bf_lo(q.z));
            x[4 * c + 3] = fmaf(tf, bf_hi(q.w), x[4 * c + 3] + bf_lo(q.w));
        }
    }

    float4* op4 = reinterpret_cast<float4*>(out + ((size_t)b * N_NEU + n) * D_DIM + h * 16);
#pragma unroll
    for (int i = 0; i < 4; ++i)
        op4[i] = make_float4(x[4 * i + 0], x[4 * i + 1], x[4 * i + 2], x[4 * i + 3]);
}

extern "C" void kernel_launch(void* const* d_in, const int* in_sizes, int n_in,
                              void* d_out, int out_size, void* d_ws, size_t ws_size,
                              hipStream_t stream) {
    const float* u        = (const float*)d_in[0];
    const float* features = (const float*)d_in[1];
    const float* bias     = (const float*)d_in[2];
    const float* w_in     = (const float*)d_in[3];
    const float* b_in     = (const float*)d_in[4];
    const float* sig_w1   = (const float*)d_in[5];
    const float* sig_b1   = (const float*)d_in[6];
    const float* sig_w2   = (const float*)d_in[7];
    const float* sig_b2   = (const float*)d_in[8];
    float* out = (float*)d_out;

    char*         ws     = (char*)d_ws;
    int*          idxT   = (int*)ws;                      // 51200 B
    float*        vals2T = (float*)(ws + 51200);          // 13*512*8 = 53248 B
    unsigned int* tbl    = (unsigned int*)(ws + 107520);  // 512 KiB
    float*        cdt    = (float*)(ws + 107520 + 524288);// 16 MiB

    hipLaunchKernelGGL(pre_kernel, dim3(UPROJ_BLKS + TOPK_BLKS + TBL_BLKS), dim3(256), 0, stream,
                       u, w_in, b_in, bias, sig_b2, features, sig_w1, sig_b1, sig_w2,
                       idxT, vals2T, tbl, cdt);
    hipLaunchKernelGGL(steps_kernel, dim3(B_SZ), dim3(512), 0, stream,
                       cdt, idxT, vals2T, tbl, out);
}

// Round 9
// 98.510 us; speedup vs baseline: 1.5376x; 1.0407x over previous
//
#include <hip/hip_runtime.h>
#include <math.h>

#define N_NEU 256
#define D_DIM 32
#define KFD   16
#define KN    50
#define B_SZ  512
#define UINF  128
#define GAMMA 0.1f
#define DT    0.05f
#define NSTEP 20

#define TBL_K   4096
#define TBL_LO  (-64.0f)
#define TBL_IDL 32.0f          // 1/Delta ; Delta = 1/32, range [-64, +64)

// pre_kernel grid layout: 256 rows of u per uproj block (4 m-tiles per wave)
#define UPROJ_BLKS (B_SZ * N_NEU / 256)  // 512
#define TOPK_BLKS  N_NEU                 // 256
#define TBL_BLKS   (TBL_K * 32 / 256)    // 512

typedef __attribute__((ext_vector_type(8))) short bf16x8;
typedef __attribute__((ext_vector_type(4))) float f32x4;

__device__ __forceinline__ unsigned short f2bf(float f) {
    unsigned u = __float_as_uint(f);
    u += 0x7FFFu + ((u >> 16) & 1u);     // round-to-nearest-even
    return (unsigned short)(u >> 16);
}
__device__ __forceinline__ float bf_lo(unsigned q) { return __uint_as_float(q << 16); }
__device__ __forceinline__ float bf_hi(unsigned q) { return __uint_as_float(q & 0xFFFF0000u); }

// ---------------------------------------------------------------------------
// Fused pre-kernel: [0,512) uproj-MFMA | [512,768) topk | [768,1280) table.
// vals are written ZERO-PADDED to 56 (4 subthreads x 14 k's) in pair layout:
//   float2 [jj][n*4+s], jj<7: pair jj of subthread s of neuron n,
//   covering k = s*14 + 2*jj + p.
// ---------------------------------------------------------------------------
__global__ __launch_bounds__(256) void pre_kernel(const float* __restrict__ u,
                                                  const float* __restrict__ w_in,
                                                  const float* __restrict__ b_in,
                                                  const float* __restrict__ bias,
                                                  const float* __restrict__ sig_b2,
                                                  const float* __restrict__ features,
                                                  const float* __restrict__ sig_w1,
                                                  const float* __restrict__ sig_b1,
                                                  const float* __restrict__ sig_w2,
                                                  int* __restrict__ idxT,
                                                  float* __restrict__ vals2T,
                                                  unsigned int* __restrict__ tbl,
                                                  float* __restrict__ cdt) {
    __shared__ float fsh[N_NEU][KFD + 1];
    __shared__ float sim_sh[N_NEU];

    const int bid = blockIdx.x;

    if (bid < UPROJ_BLKS) {
        // ---- uproj via bf16 MFMA, 4 m-tiles per wave ----
        const int  wave = threadIdx.x >> 6;
        const int  lane = threadIdx.x & 63;
        const long m0   = (long)bid * 256 + (long)wave * 64;
        const int  row  = lane & 15;
        const int  kg   = lane >> 4;

        bf16x8 bfrag[2][4];
#pragma unroll
        for (int dt_ = 0; dt_ < 2; ++dt_) {
#pragma unroll
            for (int kk = 0; kk < 4; ++kk) {
                const float* wp = w_in + (dt_ * 16 + row) * UINF + kk * 32 + kg * 8;
                bf16x8 f;
#pragma unroll
                for (int e = 0; e < 8; ++e) f[e] = (short)f2bf(wp[e]);
                bfrag[dt_][kk] = f;
            }
        }

        f32x4 acc[4][2];
#pragma unroll
        for (int t4 = 0; t4 < 4; ++t4) {
            acc[t4][0] = (f32x4){0.f, 0.f, 0.f, 0.f};
            acc[t4][1] = (f32x4){0.f, 0.f, 0.f, 0.f};
        }

#pragma unroll
        for (int t4 = 0; t4 < 4; ++t4) {
#pragma unroll
            for (int kk = 0; kk < 4; ++kk) {
                const float* up = u + (m0 + t4 * 16 + row) * UINF + kk * 32 + kg * 8;
                const float4 a0 = *reinterpret_cast<const float4*>(up);
                const float4 a1 = *reinterpret_cast<const float4*>(up + 4);
                bf16x8 af;
                af[0] = (short)f2bf(a0.x); af[1] = (short)f2bf(a0.y);
                af[2] = (short)f2bf(a0.z); af[3] = (short)f2bf(a0.w);
                af[4] = (short)f2bf(a1.x); af[5] = (short)f2bf(a1.y);
                af[6] = (short)f2bf(a1.z); af[7] = (short)f2bf(a1.w);
                acc[t4][0] = __builtin_amdgcn_mfma_f32_16x16x32_bf16(af, bfrag[0][kk], acc[t4][0], 0, 0, 0);
                acc[t4][1] = __builtin_amdgcn_mfma_f32_16x16x32_bf16(af, bfrag[1][kk], acc[t4][1], 0, 0, 0);
            }
        }

        const int   d0   = row;
        const int   d1   = 16 + row;
        const float add0 = b_in[d0] + sig_b2[d0];
        const float add1 = b_in[d1] + sig_b2[d1];
#pragma unroll
        for (int t4 = 0; t4 < 4; ++t4) {
#pragma unroll
            for (int r = 0; r < 4; ++r) {
                const long m  = m0 + t4 * 16 + kg * 4 + r;
                const int  nn = (int)(m & (N_NEU - 1));
                cdt[m * D_DIM + d0] = DT * (acc[t4][0][r] + add0 + bias[nn * D_DIM + d0]);
                cdt[m * D_DIM + d1] = DT * (acc[t4][1][r] + add1 + bias[nn * D_DIM + d1]);
            }
        }
    } else if (bid < UPROJ_BLKS + TOPK_BLKS) {
        // ---- topk ----
        const int n = bid - UPROJ_BLKS;
        const int j = threadIdx.x;

        float v[KFD];
        float s = 0.f;
#pragma unroll
        for (int d = 0; d < KFD; ++d) { v[d] = features[j * KFD + d]; s = fmaf(v[d], v[d], s); }
        const float nrm = sqrtf(s);
#pragma unroll
        for (int d = 0; d < KFD; ++d) fsh[j][d] = v[d] / nrm;
        __syncthreads();

        float dot = 0.f;
#pragma unroll
        for (int d = 0; d < KFD; ++d) dot = fmaf(fsh[n][d], fsh[j][d], dot);
        sim_sh[j] = dot;
        __syncthreads();

        if (j < 64) {
            float l0 = sim_sh[j];
            float l1 = sim_sh[j + 64];
            float l2 = sim_sh[j + 128];
            float l3 = sim_sh[j + 192];
            for (int k = 0; k < KN; ++k) {
                float bv = l0; int bi = j;
                if (l1 > bv) { bv = l1; bi = j + 64; }
                if (l2 > bv) { bv = l2; bi = j + 128; }
                if (l3 > bv) { bv = l3; bi = j + 192; }
                for (int off = 32; off > 0; off >>= 1) {
                    float ov = __shfl_xor(bv, off, 64);
                    int   oi = __shfl_xor(bi, off, 64);
                    if (ov > bv || (ov == bv && oi < bi)) { bv = ov; bi = oi; }
                }
                if (j == 0) {
                    const int s_ = k / 14;
                    const int r_ = k - 14 * s_;
                    vals2T[((r_ >> 1) * 1024 + n * 4 + s_) * 2 + (r_ & 1)] = bv;
                    idxT[k * N_NEU + n] = bi;
                }
                if ((bi & 63) == j) {
                    const int q = bi >> 6;
                    if      (q == 0) l0 = -INFINITY;
                    else if (q == 1) l1 = -INFINITY;
                    else if (q == 2) l2 = -INFINITY;
                    else             l3 = -INFINITY;
                }
            }
            if (j == 0) {   // zero-pad k = 50..55 (subthread 3, r = 8..13)
#pragma unroll
                for (int k = 50; k < 56; ++k) {
                    const int r_ = k - 42;
                    vals2T[((r_ >> 1) * 1024 + n * 4 + 3) * 2 + (r_ & 1)] = 0.f;
                }
            }
        }
    } else {
        // ---- mlp table ----
        const int gid = (bid - UPROJ_BLKS - TOPK_BLKS) * 256 + threadIdx.x;  // k*32+d
        const int k = gid >> 5, d = gid & 31;
        const float s0 = TBL_LO + (float)k / TBL_IDL;
        const float s1 = s0 + 1.0f / TBL_IDL;
        float g0 = 0.f, g1 = 0.f;
#pragma unroll
        for (int j = 0; j < 16; ++j) {
            const float w1 = sig_w1[j], b1 = sig_b1[j], w2 = sig_w2[d * 16 + j];
            const float h0 = fmaf(s0, w1, b1);
            const float h1 = fmaf(s1, w1, b1);
            const float e0 = 0.5f * h0 * (1.0f + erff(h0 * 0.70710678118654752f));
            const float e1 = 0.5f * h1 * (1.0f + erff(h1 * 0.70710678118654752f));
            g0 = fmaf(e0, w2, g0);
            g1 = fmaf(e1, w2, g1);
        }
        g0 *= DT; g1 *= DT;
        tbl[gid] = (unsigned int)f2bf(g0) | ((unsigned int)f2bf(g1 - g0) << 16);
    }
}

// ---------------------------------------------------------------------------
// Steps kernel v9: TWO batches per block via bf16-packed activities.
// Grid 256 x 1024 threads: block = batches (2*blk, 2*blk+1).
// Thread t: neuron n = t>>2, sub s = t&3; s = bb*2 + h (batch-of-pair,
// dim-half). Each thread owns x[16] (one batch, 16 dims) and 14 of the 56
// zero-padded gathers. a_sh[n] holds u32 = bf16(a_b0) | bf16(a_b1)<<16 —
// one b32 gather serves BOTH batches: LDS instr/thread-step 39 -> 21,
// conflicts/batch halve (the round-8 phase-locked LDS phase shrinks).
// Reduces via shfl_xor(.,1)/(.,2) within the 4-lane group. 16 waves/CU.
// ---------------------------------------------------------------------------
__global__ __launch_bounds__(1024) void steps_kernel(const float* __restrict__ cdt,
                                                     const int* __restrict__ idxT,
                                                     const float* __restrict__ vals2T,
                                                     const unsigned int* __restrict__ tbl,
                                                     float* __restrict__ out) {
    __shared__ unsigned int a_sh[2][N_NEU];        // packed 2-batch bf16
    __shared__ float2 vals_sh[7 * 1024];           // 57344 B, [jj][n*4+s]

    const int t  = threadIdx.x;
    const int n  = t >> 2;
    const int s  = t & 3;
    const int bb = s >> 1;
    const int h  = s & 1;
    const int b  = blockIdx.x * 2 + bb;

    const float2* v2g = reinterpret_cast<const float2*>(vals2T);
    for (int i = t; i < 7 * 1024; i += 1024) vals_sh[i] = v2g[i];

    // this thread's 14 neighbor indices (k = s*14 + j), packed 4x8-bit
    unsigned int idxp[4];
#pragma unroll
    for (int w = 0; w < 4; ++w) idxp[w] = 0u;
#pragma unroll
    for (int j = 0; j < 14; ++j) {
        const int k = s * 14 + j;
        const unsigned int ii = (k < KN) ? (unsigned int)idxT[k * N_NEU + n] : 0u;
        idxp[j >> 2] |= ii << ((j & 3) * 8);
    }

    float x[16], ccdt[16];
    const float4* cp4 = reinterpret_cast<const float4*>(cdt + ((size_t)b * N_NEU + n) * D_DIM + h * 16);
#pragma unroll
    for (int i = 0; i < 4; ++i) {
        const float4 cv = cp4[i];
        ccdt[4 * i + 0] = cv.x; ccdt[4 * i + 1] = cv.y;
        ccdt[4 * i + 2] = cv.z; ccdt[4 * i + 3] = cv.w;
    }
#pragma unroll
    for (int d = 0; d < 16; ++d) x[d] = 0.f;
    __syncthreads();   // vals_sh staged

    const float K1 = 1.0f - DT * GAMMA;   // 0.995

    for (int st = 0; st < NSTEP; ++st) {
        // ---- firing rate: partial norm + h-pair exchange ----
        float nh = 0.f;
#pragma unroll
        for (int d = 0; d < 16; ++d) nh = fmaf(x[d], x[d], nh);
        const float nfull = nh + __shfl_xor(nh, 1, 64) + 1e-12f;
        const float z = sqrtf(nfull);
        const float a = 1.0f - 2.0f / (__expf(2.0f * z) + 1.0f);   // tanh(z), z>=0

        const float ao = __shfl_xor(a, 2, 64);     // other batch's a (same h)
        const int buf = st & 1;
        if (s == 0) a_sh[buf][n] = (unsigned int)f2bf(a) | ((unsigned int)f2bf(ao) << 16);

        // x decay update is gather-independent: do it BEFORE the barrier so
        // it overlaps other waves' arrival.
#pragma unroll
        for (int d = 0; d < 16; ++d) x[d] = fmaf(K1, x[d], ccdt[d]);

        __syncthreads();            // packed a visible; WAR safe via dbuf

        // ---- 14 packed gathers (7 float2 vals), both batches at once ----
        float sA0 = 0.f, sA1 = 0.f, sB0 = 0.f, sB1 = 0.f;
#pragma unroll
        for (int jj = 0; jj < 7; ++jj) {
            const float2 vv = vals_sh[jj * 1024 + t];
            const int j0 = 2 * jj, j1 = 2 * jj + 1;
            const int i0 = (int)((idxp[j0 >> 2] >> ((j0 & 3) * 8)) & 255u);
            const int i1 = (int)((idxp[j1 >> 2] >> ((j1 & 3) * 8)) & 255u);
            const unsigned int p0 = a_sh[buf][i0];
            const unsigned int p1 = a_sh[buf][i1];
            sA0 = fmaf(bf_lo(p0), vv.x, sA0);
            sB0 = fmaf(bf_hi(p0), vv.x, sB0);
            sA1 = fmaf(bf_lo(p1), vv.y, sA1);
            sB1 = fmaf(bf_hi(p1), vv.y, sB1);
        }
        float sA = sA0 + sA1;
        float sB = sB0 + sB1;
        sA += __shfl_xor(sA, 1, 64); sA += __shfl_xor(sA, 2, 64);
        sB += __shfl_xor(sB, 1, 64); sB += __shfl_xor(sB, 2, 64);
        const float syn = bb ? sB : sA;

        // ---- sigma MLP via table lerp (this thread's 16 dims) ----
        const float uu = fmaf(syn, TBL_IDL, -TBL_LO * TBL_IDL);
        int i = (int)floorf(uu);
        i = (i < 0) ? 0 : (i > TBL_K - 2 ? TBL_K - 2 : i);
        const float tf = uu - (float)i;
        const uint4* rp = reinterpret_cast<const uint4*>(tbl + (size_t)i * 32 + h * 16);
#pragma unroll
        for (int c = 0; c < 4; ++c) {
            const uint4 q = rp[c];
            x[4 * c + 0] = fmaf(tf, bf_hi(q.x), x[4 * c + 0] + bf_lo(q.x));
            x[4 * c + 1] = fmaf(tf, bf_hi(q.y), x[4 * c + 1] + bf_lo(q.y));
            x[4 * c + 2] = fmaf(tf, bf_hi(q.z), x[4 * c + 2] + bf_lo(q.z));
            x[4 * c + 3] = fmaf(tf, bf_hi(q.w), x[4 * c + 3] + bf_lo(q.w));
        }
    }

    float4* op4 = reinterpret_cast<float4*>(out + ((size_t)b * N_NEU + n) * D_DIM + h * 16);
#pragma unroll
    for (int i = 0; i < 4; ++i)
        op4[i] = make_float4(x[4 * i + 0], x[4 * i + 1], x[4 * i + 2], x[4 * i + 3]);
}

extern "C" void kernel_launch(void* const* d_in, const int* in_sizes, int n_in,
                              void* d_out, int out_size, void* d_ws, size_t ws_size,
                              hipStream_t stream) {
    const float* u        = (const float*)d_in[0];
    const float* features = (const float*)d_in[1];
    const float* bias     = (const float*)d_in[2];
    const float* w_in     = (const float*)d_in[3];
    const float* b_in     = (const float*)d_in[4];
    const float* sig_w1   = (const float*)d_in[5];
    const float* sig_b1   = (const float*)d_in[6];
    const float* sig_w2   = (const float*)d_in[7];
    const float* sig_b2   = (const float*)d_in[8];
    float* out = (float*)d_out;

    char*         ws     = (char*)d_ws;
    int*          idxT   = (int*)ws;                      // 51200 B
    float*        vals2T = (float*)(ws + 51200);          // 7*1024*8 = 57344 B
    unsigned int* tbl    = (unsigned int*)(ws + 110592);  // 512 KiB
    float*        cdt    = (float*)(ws + 110592 + 524288);// 16 MiB

    hipLaunchKernelGGL(pre_kernel, dim3(UPROJ_BLKS + TOPK_BLKS + TBL_BLKS), dim3(256), 0, stream,
                       u, w_in, b_in, bias, sig_b2, features, sig_w1, sig_b1, sig_w2,
                       idxT, vals2T, tbl, cdt);
    hipLaunchKernelGGL(steps_kernel, dim3(B_SZ / 2), dim3(1024), 0, stream,
                       cdt, idxT, vals2T, tbl, out);
}

// Round 10
// 97.055 us; speedup vs baseline: 1.5606x; 1.0150x over previous
//
#include <hip/hip_runtime.h>
#include <math.h>

#define N_NEU 256
#define D_DIM 32
#define KFD   16
#define KN    50
#define B_SZ  512
#define UINF  128
#define GAMMA 0.1f
#define DT    0.05f
#define NSTEP 20

#define TBL_K   4096
#define TBL_LO  (-64.0f)
#define TBL_IDL 32.0f          // 1/Delta ; Delta = 1/32, range [-64, +64)

// pre_kernel grid layout: 256 rows of u per uproj block (4 m-tiles per wave)
#define UPROJ_BLKS (B_SZ * N_NEU / 256)  // 512
#define TOPK_BLKS  N_NEU                 // 256
#define TBL_BLKS   (TBL_K * 32 / 256)    // 512

typedef __attribute__((ext_vector_type(8))) short bf16x8;
typedef __attribute__((ext_vector_type(4))) float f32x4;

__device__ __forceinline__ unsigned short f2bf(float f) {
    unsigned u = __float_as_uint(f);
    u += 0x7FFFu + ((u >> 16) & 1u);     // round-to-nearest-even
    return (unsigned short)(u >> 16);
}
__device__ __forceinline__ float bf_lo(unsigned q) { return __uint_as_float(q << 16); }
__device__ __forceinline__ float bf_hi(unsigned q) { return __uint_as_float(q & 0xFFFF0000u); }

// ---------------------------------------------------------------------------
// Fused pre-kernel: [0,512) uproj-MFMA | [512,768) topk | [768,1280) table.
// uproj: explicit depth-4 software pipeline over 16 (t4,kk) units — 8 float4
// u-loads always in flight (round-9: VGPR=76 showed the compiler kept only a
// few, exposing ~900-cyc HBM latency; this buys the regs explicitly).
// ---------------------------------------------------------------------------
__global__ __launch_bounds__(256) void pre_kernel(const float* __restrict__ u,
                                                  const float* __restrict__ w_in,
                                                  const float* __restrict__ b_in,
                                                  const float* __restrict__ bias,
                                                  const float* __restrict__ sig_b2,
                                                  const float* __restrict__ features,
                                                  const float* __restrict__ sig_w1,
                                                  const float* __restrict__ sig_b1,
                                                  const float* __restrict__ sig_w2,
                                                  int* __restrict__ idxT,
                                                  float* __restrict__ vals2T,
                                                  unsigned int* __restrict__ tbl,
                                                  float* __restrict__ cdt) {
    __shared__ float fsh[N_NEU][KFD + 1];
    __shared__ float sim_sh[N_NEU];

    const int bid = blockIdx.x;

    if (bid < UPROJ_BLKS) {
        // ---- uproj via bf16 MFMA, 4 m-tiles per wave, pipelined loads ----
        const int  wave = threadIdx.x >> 6;
        const int  lane = threadIdx.x & 63;
        const long m0   = (long)bid * 256 + (long)wave * 64;
        const int  row  = lane & 15;
        const int  kg   = lane >> 4;

        bf16x8 bfrag[2][4];
#pragma unroll
        for (int dt_ = 0; dt_ < 2; ++dt_) {
#pragma unroll
            for (int kk = 0; kk < 4; ++kk) {
                const float* wp = w_in + (dt_ * 16 + row) * UINF + kk * 32 + kg * 8;
                bf16x8 f;
#pragma unroll
                for (int e = 0; e < 8; ++e) f[e] = (short)f2bf(wp[e]);
                bfrag[dt_][kk] = f;
            }
        }

        f32x4 acc[4][2];
#pragma unroll
        for (int t4 = 0; t4 < 4; ++t4) {
            acc[t4][0] = (f32x4){0.f, 0.f, 0.f, 0.f};
            acc[t4][1] = (f32x4){0.f, 0.f, 0.f, 0.f};
        }

        const float* ub = u + (m0 + row) * UINF + kg * 8;
        float4 pa[4][2];                 // 4-stage rotating load buffer (32 VGPR)

        // prologue: stage units 0..3 (t4=0, kk=0..3)
#pragma unroll
        for (int st = 0; st < 4; ++st) {
            const float* up = ub + st * 32;
            pa[st][0] = *reinterpret_cast<const float4*>(up);
            pa[st][1] = *reinterpret_cast<const float4*>(up + 4);
        }

#pragma unroll
        for (int uu = 0; uu < 16; ++uu) {
            const int t4 = uu >> 2, kk = uu & 3;
            const int st = uu & 3;
            const float4 a0 = pa[st][0];
            const float4 a1 = pa[st][1];
            if (uu < 12) {               // prefetch unit uu+4 into freed stage
                const int un = uu + 4;
                const float* up = ub + (long)(un >> 2) * 16 * UINF + (un & 3) * 32;
                pa[st][0] = *reinterpret_cast<const float4*>(up);
                pa[st][1] = *reinterpret_cast<const float4*>(up + 4);
            }
            bf16x8 af;
            af[0] = (short)f2bf(a0.x); af[1] = (short)f2bf(a0.y);
            af[2] = (short)f2bf(a0.z); af[3] = (short)f2bf(a0.w);
            af[4] = (short)f2bf(a1.x); af[5] = (short)f2bf(a1.y);
            af[6] = (short)f2bf(a1.z); af[7] = (short)f2bf(a1.w);
            acc[t4][0] = __builtin_amdgcn_mfma_f32_16x16x32_bf16(af, bfrag[0][kk], acc[t4][0], 0, 0, 0);
            acc[t4][1] = __builtin_amdgcn_mfma_f32_16x16x32_bf16(af, bfrag[1][kk], acc[t4][1], 0, 0, 0);
        }

        const int   d0   = row;
        const int   d1   = 16 + row;
        const float add0 = b_in[d0] + sig_b2[d0];
        const float add1 = b_in[d1] + sig_b2[d1];
#pragma unroll
        for (int t4 = 0; t4 < 4; ++t4) {
#pragma unroll
            for (int r = 0; r < 4; ++r) {
                const long m  = m0 + t4 * 16 + kg * 4 + r;
                const int  nn = (int)(m & (N_NEU - 1));
                cdt[m * D_DIM + d0] = DT * (acc[t4][0][r] + add0 + bias[nn * D_DIM + d0]);
                cdt[m * D_DIM + d1] = DT * (acc[t4][1][r] + add1 + bias[nn * D_DIM + d1]);
            }
        }
    } else if (bid < UPROJ_BLKS + TOPK_BLKS) {
        // ---- topk ----
        const int n = bid - UPROJ_BLKS;
        const int j = threadIdx.x;

        float v[KFD];
        float s = 0.f;
#pragma unroll
        for (int d = 0; d < KFD; ++d) { v[d] = features[j * KFD + d]; s = fmaf(v[d], v[d], s); }
        const float nrm = sqrtf(s);
#pragma unroll
        for (int d = 0; d < KFD; ++d) fsh[j][d] = v[d] / nrm;
        __syncthreads();

        float dot = 0.f;
#pragma unroll
        for (int d = 0; d < KFD; ++d) dot = fmaf(fsh[n][d], fsh[j][d], dot);
        sim_sh[j] = dot;
        __syncthreads();

        if (j < 64) {
            float l0 = sim_sh[j];
            float l1 = sim_sh[j + 64];
            float l2 = sim_sh[j + 128];
            float l3 = sim_sh[j + 192];
            for (int k = 0; k < KN; ++k) {
                float bv = l0; int bi = j;
                if (l1 > bv) { bv = l1; bi = j + 64; }
                if (l2 > bv) { bv = l2; bi = j + 128; }
                if (l3 > bv) { bv = l3; bi = j + 192; }
                for (int off = 32; off > 0; off >>= 1) {
                    float ov = __shfl_xor(bv, off, 64);
                    int   oi = __shfl_xor(bi, off, 64);
                    if (ov > bv || (ov == bv && oi < bi)) { bv = ov; bi = oi; }
                }
                if (j == 0) {
                    const int s_ = k / 14;
                    const int r_ = k - 14 * s_;
                    vals2T[((r_ >> 1) * 1024 + n * 4 + s_) * 2 + (r_ & 1)] = bv;
                    idxT[k * N_NEU + n] = bi;
                }
                if ((bi & 63) == j) {
                    const int q = bi >> 6;
                    if      (q == 0) l0 = -INFINITY;
                    else if (q == 1) l1 = -INFINITY;
                    else if (q == 2) l2 = -INFINITY;
                    else             l3 = -INFINITY;
                }
            }
            if (j == 0) {   // zero-pad k = 50..55 (subthread 3, r = 8..13)
#pragma unroll
                for (int k = 50; k < 56; ++k) {
                    const int r_ = k - 42;
                    vals2T[((r_ >> 1) * 1024 + n * 4 + 3) * 2 + (r_ & 1)] = 0.f;
                }
            }
        }
    } else {
        // ---- mlp table ----
        const int gid = (bid - UPROJ_BLKS - TOPK_BLKS) * 256 + threadIdx.x;  // k*32+d
        const int k = gid >> 5, d = gid & 31;
        const float s0 = TBL_LO + (float)k / TBL_IDL;
        const float s1 = s0 + 1.0f / TBL_IDL;
        float g0 = 0.f, g1 = 0.f;
#pragma unroll
        for (int j = 0; j < 16; ++j) {
            const float w1 = sig_w1[j], b1 = sig_b1[j], w2 = sig_w2[d * 16 + j];
            const float h0 = fmaf(s0, w1, b1);
            const float h1 = fmaf(s1, w1, b1);
            const float e0 = 0.5f * h0 * (1.0f + erff(h0 * 0.70710678118654752f));
            const float e1 = 0.5f * h1 * (1.0f + erff(h1 * 0.70710678118654752f));
            g0 = fmaf(e0, w2, g0);
            g1 = fmaf(e1, w2, g1);
        }
        g0 *= DT; g1 *= DT;
        tbl[gid] = (unsigned int)f2bf(g0) | ((unsigned int)f2bf(g1 - g0) << 16);
    }
}

// ---------------------------------------------------------------------------
// Steps kernel v10: r9 structure (2 batches/block via bf16-packed a, 1024
// threads, 16 waves/CU) + step-invariant gather ADDRESSES precomputed into
// 14 LDS pointers (zero index-extraction VALU in the gather loop; the
// double-buffer select folds into the ds_read offset immediate because the
// step body is instantiated with literal buf 0/1) + 2-acc tree norm + trunc
// instead of floorf.
// ---------------------------------------------------------------------------
__global__ __launch_bounds__(1024) void steps_kernel(const float* __restrict__ cdt,
                                                     const int* __restrict__ idxT,
                                                     const float* __restrict__ vals2T,
                                                     const unsigned int* __restrict__ tbl,
                                                     float* __restrict__ out) {
    __shared__ unsigned int a_sh[2][N_NEU];        // packed 2-batch bf16
    __shared__ float2 vals_sh[7 * 1024];           // 57344 B, [jj][n*4+s]

    const int t  = threadIdx.x;
    const int n  = t >> 2;
    const int s  = t & 3;
    const int bb = s >> 1;
    const int h  = s & 1;
    const int b  = blockIdx.x * 2 + bb;

    const float2* v2g = reinterpret_cast<const float2*>(vals2T);
    for (int i = t; i < 7 * 1024; i += 1024) vals_sh[i] = v2g[i];

    // step-invariant gather pointers into a_sh[0][.] (buf 1 = +N_NEU elements)
    const unsigned int* gp[14];
#pragma unroll
    for (int j = 0; j < 14; ++j) {
        const int k = s * 14 + j;
        const int ii = (k < KN) ? idxT[k * N_NEU + n] : 0;
        gp[j] = &a_sh[0][ii];
    }

    float x[16], ccdt[16];
    const float4* cp4 = reinterpret_cast<const float4*>(cdt + ((size_t)b * N_NEU + n) * D_DIM + h * 16);
#pragma unroll
    for (int i = 0; i < 4; ++i) {
        const float4 cv = cp4[i];
        ccdt[4 * i + 0] = cv.x; ccdt[4 * i + 1] = cv.y;
        ccdt[4 * i + 2] = cv.z; ccdt[4 * i + 3] = cv.w;
    }
#pragma unroll
    for (int d = 0; d < 16; ++d) x[d] = 0.f;
    __syncthreads();   // vals_sh staged

    const float K1 = 1.0f - DT * GAMMA;   // 0.995

#define STEP_BODY(BUF)                                                          \
    {                                                                           \
        float nh0 = 0.f, nh1 = 0.f;                                             \
        _Pragma("unroll")                                                       \
        for (int d = 0; d < 16; d += 2) {                                       \
            nh0 = fmaf(x[d], x[d], nh0);                                        \
            nh1 = fmaf(x[d + 1], x[d + 1], nh1);                                \
        }                                                                       \
        const float nh = nh0 + nh1;                                             \
        const float nfull = nh + __shfl_xor(nh, 1, 64) + 1e-12f;                \
        const float z = sqrtf(nfull);                                           \
        const float a = 1.0f - 2.0f / (__expf(2.0f * z) + 1.0f);                \
        const float ao = __shfl_xor(a, 2, 64);                                  \
        if (s == 0) a_sh[BUF][n] = (unsigned int)f2bf(a) | ((unsigned int)f2bf(ao) << 16); \
        _Pragma("unroll")                                                       \
        for (int d = 0; d < 16; ++d) x[d] = fmaf(K1, x[d], ccdt[d]);            \
        __syncthreads();                                                        \
        float sA0 = 0.f, sA1 = 0.f, sB0 = 0.f, sB1 = 0.f;                       \
        _Pragma("unroll")                                                       \
        for (int jj = 0; jj < 7; ++jj) {                                        \
            const float2 vv = vals_sh[jj * 1024 + t];                           \
            const unsigned int p0 = gp[2 * jj][(BUF) * N_NEU];                  \
            const unsigned int p1 = gp[2 * jj + 1][(BUF) * N_NEU];              \
            sA0 = fmaf(bf_lo(p0), vv.x, sA0);                                   \
            sB0 = fmaf(bf_hi(p0), vv.x, sB0);                                   \
            sA1 = fmaf(bf_lo(p1), vv.y, sA1);                                   \
            sB1 = fmaf(bf_hi(p1), vv.y, sB1);                                   \
        }                                                                       \
        float sA = sA0 + sA1;                                                   \
        float sB = sB0 + sB1;                                                   \
        sA += __shfl_xor(sA, 1, 64); sA += __shfl_xor(sA, 2, 64);               \
        sB += __shfl_xor(sB, 1, 64); sB += __shfl_xor(sB, 2, 64);               \
        const float syn = bb ? sB : sA;                                         \
        const float uu = fmaf(syn, TBL_IDL, -TBL_LO * TBL_IDL);                 \
        int i = (int)uu;                                                        \
        i = (i < 0) ? 0 : (i > TBL_K - 2 ? TBL_K - 2 : i);                      \
        const float tf = uu - (float)i;                                         \
        const uint4* rp = reinterpret_cast<const uint4*>(tbl + (size_t)i * 32 + h * 16); \
        _Pragma("unroll")                                                       \
        for (int c = 0; c < 4; ++c) {                                           \
            const uint4 q = rp[c];                                              \
            x[4 * c + 0] = fmaf(tf, bf_hi(q.x), x[4 * c + 0] + bf_lo(q.x));     \
            x[4 * c + 1] = fmaf(tf, bf_hi(q.y), x[4 * c + 1] + bf_lo(q.y));     \
            x[4 * c + 2] = fmaf(tf, bf_hi(q.z), x[4 * c + 2] + bf_lo(q.z));     \
            x[4 * c + 3] = fmaf(tf, bf_hi(q.w), x[4 * c + 3] + bf_lo(q.w));     \
        }                                                                       \
    }

    for (int it = 0; it < NSTEP / 2; ++it) {
        STEP_BODY(0);
        STEP_BODY(1);
    }
#undef STEP_BODY

    float4* op4 = reinterpret_cast<float4*>(out + ((size_t)b * N_NEU + n) * D_DIM + h * 16);
#pragma unroll
    for (int i = 0; i < 4; ++i)
        op4[i] = make_float4(x[4 * i + 0], x[4 * i + 1], x[4 * i + 2], x[4 * i + 3]);
}

extern "C" void kernel_launch(void* const* d_in, const int* in_sizes, int n_in,
                              void* d_out, int out_size, void* d_ws, size_t ws_size,
                              hipStream_t stream) {
    const float* u        = (const float*)d_in[0];
    const float* features = (const float*)d_in[1];
    const float* bias     = (const float*)d_in[2];
    const float* w_in     = (const float*)d_in[3];
    const float* b_in     = (const float*)d_in[4];
    const float* sig_w1   = (const float*)d_in[5];
    const float* sig_b1   = (const float*)d_in[6];
    const float* sig_w2   = (const float*)d_in[7];
    const float* sig_b2   = (const float*)d_in[8];
    float* out = (float*)d_out;

    char*         ws     = (char*)d_ws;
    int*          idxT   = (int*)ws;                      // 51200 B
    float*        vals2T = (float*)(ws + 51200);          // 7*1024*8 = 57344 B
    unsigned int* tbl    = (unsigned int*)(ws + 110592);  // 512 KiB
    float*        cdt    = (float*)(ws + 110592 + 524288);// 16 MiB

    hipLaunchKernelGGL(pre_kernel, dim3(UPROJ_BLKS + TOPK_BLKS + TBL_BLKS), dim3(256), 0, stream,
                       u, w_in, b_in, bias, sig_b2, features, sig_w1, sig_b1, sig_w2,
                       idxT, vals2T, tbl, cdt);
    hipLaunchKernelGGL(steps_kernel, dim3(B_SZ / 2), dim3(1024), 0, stream,
                       cdt, idxT, vals2T, tbl, out);
}